// Round 6
// baseline (644.421 us; speedup 1.0000x reference)
//
#include <hip/hip_runtime.h>
#include <hip/hip_fp16.h>

// 21-qubit batched (B=4) state-vector simulator.
// R6: single persistent fused kernel (512 blocks x 512 thr = exact device
// capacity at 64KB LDS -> guaranteed co-residency), 6 phases separated by
// manual PER-BATCH global barriers (4 independent 128-block barriers,
// device-scope atomics + __threadfence for cross-XCD visibility).
// Phase bodies identical to R5 (verified): fp16 global state, f32 LDS tiles,
// sigma-relayout consecutive-bit windows, b128 reads / b32 scatter writes.

#define NQ 21
#define SHC(q) __shfl(cv, (q)), __shfl(sv, (q))

__device__ constexpr int PH2(int slot) {
  int blk = slot >> 2;
  blk ^= ((blk >> 3) & 7) ^ ((blk >> 6) & 7);
  return (blk << 2) | (slot & 3);
}

template<int Q>
__device__ __forceinline__ void ry32(float* v, float c, float s) {
#pragma unroll
  for (int k = 0; k < 16; ++k) {
    int l0 = ((k >> Q) << (Q + 1)) | (k & ((1 << Q) - 1));
    int l1 = l0 | (1 << Q);
    float a0 = v[l0], a1 = v[l1];
    v[l0] = c * a0 - s * a1;
    v[l1] = s * a0 + c * a1;
  }
}

template<int C, int T>
__device__ __forceinline__ void cnot32(float* v) {
  constexpr int lo = (C < T) ? C : T;
  constexpr int hi = (C < T) ? T : C;
#pragma unroll
  for (int k = 0; k < 8; ++k) {
    int i1 = ((k >> lo) << (lo + 1)) | (k & ((1 << lo) - 1));
    int i2 = ((i1 >> hi) << (hi + 1)) | (i1 & ((1 << hi) - 1));
    int a = i2 | (1 << C);   // control = 1, target = 0
    int b = a | (1 << T);
    float tmp = v[a]; v[a] = v[b]; v[b] = tmp;
  }
}

// 4 amps (8B) fp16 <-> 4 f32 regs
__device__ __forceinline__ void ld4(const uint2* __restrict__ g, int idx, float* dst) {
  uint2 r = g[idx];
  __half2 h0 = *reinterpret_cast<__half2*>(&r.x);
  __half2 h1 = *reinterpret_cast<__half2*>(&r.y);
  float2 f0 = __half22float2(h0), f1 = __half22float2(h1);
  dst[0] = f0.x; dst[1] = f0.y; dst[2] = f1.x; dst[3] = f1.y;
}
__device__ __forceinline__ uint2 pk4(const float* src) {
  __half2 h0 = __floats2half2_rn(src[0], src[1]);
  __half2 h1 = __floats2half2_rn(src[2], src[3]);
  uint2 r;
  r.x = *reinterpret_cast<unsigned int*>(&h0);
  r.y = *reinterpret_cast<unsigned int*>(&h1);
  return r;
}

#define A1 (tid | (rr << 9))
#define GH(l4) (((l4) & 0xF) | (t << 4) | (((l4) >> 4) << 11))

// ---------------- per-batch global barrier (128 blocks) ----------------
// bar[0] = cnt, bar[1] = gen. Self-resetting; gen monotonic across replays.
__device__ __forceinline__ void gbar(unsigned* bar) {
  __syncthreads();
  if (threadIdx.x == 0) {
    __threadfence();   // release this block's state writes (agent scope, wb L2)
    unsigned g = __hip_atomic_load(bar + 1, __ATOMIC_RELAXED, __HIP_MEMORY_SCOPE_AGENT);
    if (__hip_atomic_fetch_add(bar, 1u, __ATOMIC_ACQ_REL, __HIP_MEMORY_SCOPE_AGENT) == 127u) {
      __hip_atomic_store(bar, 0u, __ATOMIC_RELAXED, __HIP_MEMORY_SCOPE_AGENT);
      __hip_atomic_fetch_add(bar + 1, 1u, __ATOMIC_RELEASE, __HIP_MEMORY_SCOPE_AGENT);
    } else {
      while (__hip_atomic_load(bar + 1, __ATOMIC_ACQUIRE, __HIP_MEMORY_SCOPE_AGENT) == g)
        __builtin_amdgcn_s_sleep(2);
    }
    __threadfence();   // acquire: invalidate stale lines before next phase reads
  }
  __syncthreads();
}

// ---------------- L pass body (R5-verified) ----------------
template<bool INIT>
__device__ __forceinline__ void dL(const float* __restrict__ x,
                                   const float* __restrict__ w,
                                   unsigned long long stp, float* __restrict__ s) {
  float4* s4 = reinterpret_cast<float4*>(s);
  const int tid = threadIdx.x, lane = tid & 63;
  const int b = blockIdx.x >> 7, t = blockIdx.x & 127;
  float cv = 1.f, sv = 0.f;
  if (lane < NQ) sincosf(0.5f * w[lane], &sv, &cv);
  uint2* g2 = reinterpret_cast<uint2*>(stp) + ((size_t)b << 19) + ((size_t)t << 12);
  float v[32];
  float4* v4 = reinterpret_cast<float4*>(v);

  // ---- S1: window {0,1,11,12,13}: C(13,12),(12,11); RY 13(q7),12(q8) ----
  if (INIT) {
    float cx = 1.f, sx = 0.f;
    if (lane < NQ) sincosf(0.5f * x[b * NQ + lane], &sx, &cx);
    float Qp = 1.f;
#pragma unroll
    for (int i = 0; i < 9; ++i) {            // tid bit i -> g(2+i) -> qubit 18-i
      float cq = __shfl(cx, 18 - i), sq = __shfl(sx, 18 - i);
      Qp *= ((tid >> i) & 1) ? sq : cq;
    }
    float hfac[2];
#pragma unroll
    for (int bb = 0; bb < 2; ++bb) {         // g13 = bb, h = g[13..20]
      int h = (t << 1) | bb;
      int h0 = h ^ (h >> 1);                 // pre-image of high chain
      float p = 1.f;
#pragma unroll
      for (int j = 0; j < 8; ++j) {          // h0 bit j -> g(13+j) -> qubit 7-j
        float cq = __shfl(cx, 7 - j), sq = __shfl(sx, 7 - j);
        p *= ((h0 >> j) & 1) ? sq : cq;
      }
      hfac[bb] = p;
    }
    float c20 = __shfl(cx, 20), s20 = __shfl(sx, 20);
    float c19 = __shfl(cx, 19), s19 = __shfl(sx, 19);
    float c9  = __shfl(cx, 9),  s9  = __shfl(sx, 9);
    float c8  = __shfl(cx, 8),  s8  = __shfl(sx, 8);
    float w0t[4], w1t[4];
#pragma unroll
    for (int i = 0; i < 4; ++i) {
      w0t[i] = ((i & 1) ? s20 : c20) * ((i & 2) ? s19 : c19);  // amp bits 0,1
      w1t[i] = ((i & 1) ? s9  : c9 ) * ((i & 2) ? s8  : c8 );  // amp bits 11,12
    }
#pragma unroll
    for (int r = 0; r < 32; ++r)
      v[r] = hfac[(r >> 4) & 1] * w1t[(r >> 2) & 3] * w0t[r & 3] * Qp;
  } else {
#pragma unroll
    for (int rr = 0; rr < 8; ++rr) ld4(g2, A1, v + 4 * rr);
  }
  cnot32<4, 3>(v); cnot32<3, 2>(v);
  ry32<4>(v, SHC(7)); ry32<3>(v, SHC(8));
  {
    const int pb = PH2(((tid & 31) << 2) | ((tid >> 5) & 3) | (((tid >> 7) & 3) << 9));
#pragma unroll
    for (int r = 0; r < 32; ++r)
      s[pb ^ PH2(((r & 3) << 7) | ((r >> 2) << 11))] = v[r];
  }
  __syncthreads();

  // ---- S2: window {7..11}: C(11,10),(10,9),(9,8),(8,7); RY 11..8 (q9..q12) ----
  {
    const int pb = PH2(((tid & 3) << 7) | (tid & 0x7C) | ((tid >> 7) << 12));
#pragma unroll
    for (int rr = 0; rr < 8; ++rr) v4[rr] = s4[(pb ^ PH2(rr << 9)) >> 2];
  }
  cnot32<4, 3>(v); cnot32<3, 2>(v); cnot32<2, 1>(v); cnot32<1, 0>(v);
  ry32<4>(v, SHC(9)); ry32<3>(v, SHC(10)); ry32<2>(v, SHC(11)); ry32<1>(v, SHC(12));
  __syncthreads();
  {
    const int pb = PH2(((tid >> 3) & 3) | (tid & 4) | ((tid & 3) << 3) |
                       (tid & 0x60) | ((tid >> 7) << 12));
#pragma unroll
    for (int r = 0; r < 32; ++r) s[pb ^ PH2(r << 7)] = v[r];
  }
  __syncthreads();

  // ---- S3: window {3..7}: C(7,6),(6,5),(5,4),(4,3); RY 7..4 (q13..q16) ----
  {
    const int pb = PH2(((tid & 3) << 3) | (tid & 4) | ((tid >> 3) << 8));
#pragma unroll
    for (int rr = 0; rr < 8; ++rr) v4[rr] = s4[(pb ^ PH2(rr << 5)) >> 2];
  }
  cnot32<4, 3>(v); cnot32<3, 2>(v); cnot32<2, 1>(v); cnot32<1, 0>(v);
  ry32<4>(v, SHC(13)); ry32<3>(v, SHC(14)); ry32<2>(v, SHC(15)); ry32<1>(v, SHC(16));
  __syncthreads();
  {
    const int pb = PH2((tid & 7) | ((tid >> 3) << 8));
#pragma unroll
    for (int r = 0; r < 32; ++r) s[pb ^ PH2(r << 3)] = v[r];
  }
  __syncthreads();

  // ---- S4: window {0..4}: C(3,2),(2,1),(1,0); RY 3,2,1 (q17,q18,q19); store ----
  {
    const int pb = PH2(tid << 5);
#pragma unroll
    for (int rr = 0; rr < 8; ++rr) v4[rr] = s4[(pb ^ PH2(rr << 2)) >> 2];
  }
  cnot32<3, 2>(v); cnot32<2, 1>(v); cnot32<1, 0>(v);
  ry32<3>(v, SHC(17)); ry32<2>(v, SHC(18)); ry32<1>(v, SHC(19));
  {
    uint4* g4o = reinterpret_cast<uint4*>(g2);
#pragma unroll
    for (int rr = 0; rr < 8; rr += 2) {
      uint2 lo = pk4(v + 4 * rr), hi = pk4(v + 4 * rr + 4);
      uint4 o; o.x = lo.x; o.y = lo.y; o.z = hi.x; o.w = hi.y;
      g4o[((rr | (tid << 3)) >> 1)] = o;
    }
  }
}

// ---------------- H pass body (R5-verified) ----------------
__device__ __forceinline__ void dH(const float* __restrict__ w,
                                   unsigned long long stp, float* __restrict__ s) {
  float4* s4 = reinterpret_cast<float4*>(s);
  const int tid = threadIdx.x, lane = tid & 63;
  const int b = blockIdx.x >> 7, t = blockIdx.x & 127;
  float cv = 1.f, sv = 0.f;
  if (lane < NQ) sincosf(0.5f * w[lane], &sv, &cv);
  uint2* gb = reinterpret_cast<uint2*>(stp) + ((size_t)b << 19);
  float v[32];
  float4* v4 = reinterpret_cast<float4*>(v);

  // ---- HS1: wrap C(l0,l13); RY l0(q20),l13(q0),l12(q1),l11(q2); chain x2 ----
#pragma unroll
  for (int rr = 0; rr < 8; ++rr) ld4(gb, GH(A1), v + 4 * rr);
  cnot32<0, 4>(v);
  ry32<0>(v, SHC(20)); ry32<4>(v, SHC(0)); ry32<3>(v, SHC(1)); ry32<2>(v, SHC(2));
  cnot32<4, 3>(v); cnot32<3, 2>(v);
  {
    const int pb = PH2(((tid & 31) << 2) | ((tid >> 5) & 3) | (((tid >> 7) & 3) << 9));
#pragma unroll
    for (int r = 0; r < 32; ++r)
      s[pb ^ PH2(((r & 3) << 7) | ((r >> 2) << 11))] = v[r];
  }
  __syncthreads();

  // ---- HS2: RY l10(q3),l9(q4),l8(q5),l7(q6); chain C x4 ----
  {
    const int pb = PH2(((tid & 3) << 7) | (tid & 0x7C) | ((tid >> 7) << 12));
#pragma unroll
    for (int rr = 0; rr < 8; ++rr) v4[rr] = s4[(pb ^ PH2(rr << 9)) >> 2];
  }
  ry32<3>(v, SHC(3)); ry32<2>(v, SHC(4)); ry32<1>(v, SHC(5)); ry32<0>(v, SHC(6));
  cnot32<4, 3>(v); cnot32<3, 2>(v); cnot32<2, 1>(v); cnot32<1, 0>(v);
  __syncthreads();
  {
    const int pb = PH2((tid & 127) | ((tid >> 7) << 12));
#pragma unroll
    for (int r = 0; r < 32; ++r) s[pb ^ PH2(r << 7)] = v[r];
  }
  __syncthreads();

  // ---- HS3: window {l0,l1,l5,l6,l7}: chain C(l7,l6); store ----
  {
    const int pb = PH2(((tid & 7) << 2) | ((tid >> 3) << 8));
#pragma unroll
    for (int rr = 0; rr < 8; ++rr) v4[rr] = s4[(pb ^ PH2(rr << 5)) >> 2];
  }
  cnot32<4, 3>(v);
#pragma unroll
  for (int rr = 0; rr < 8; ++rr) {
    int l4 = (tid & 7) | (rr << 3) | ((tid >> 3) << 6);
    gb[GH(l4)] = pk4(v + 4 * rr);
  }
}

// ---------------- final H pass + measurement body (R5-verified) ----------------
__device__ __forceinline__ void dHfin(const float* __restrict__ w,
                                      unsigned long long stp,
                                      float* __restrict__ partial,
                                      float* __restrict__ s) {
  float4* s4 = reinterpret_cast<float4*>(s);
  const int tid = threadIdx.x, lane = tid & 63;
  const int b = blockIdx.x >> 7, t = blockIdx.x & 127;
  float cv = 1.f, sv = 0.f;
  if (lane < NQ) sincosf(0.5f * w[lane], &sv, &cv);
  const uint2* gb = reinterpret_cast<const uint2*>(stp) + ((size_t)b << 19);
  float v[32];
  float4* v4 = reinterpret_cast<float4*>(v);

  // ---- HS1f: wrap; RY l0,l13,l12,l11 ----
#pragma unroll
  for (int rr = 0; rr < 8; ++rr) ld4(gb, GH(A1), v + 4 * rr);
  cnot32<0, 4>(v);
  ry32<0>(v, SHC(20)); ry32<4>(v, SHC(0)); ry32<3>(v, SHC(1)); ry32<2>(v, SHC(2));
  {
    const int pb = PH2(((tid & 31) << 2) | ((tid >> 5) & 3) | (((tid >> 7) & 3) << 9));
#pragma unroll
    for (int r = 0; r < 32; ++r)
      s[pb ^ PH2(((r & 3) << 7) | ((r >> 2) << 11))] = v[r];
  }
  __syncthreads();

  // ---- HS2f: window {l7..l11}: RY l10(q3),l9(q4),l8(q5),l7(q6); measure ----
  {
    const int pb = PH2(((tid & 3) << 7) | (tid & 0x7C) | ((tid >> 7) << 12));
#pragma unroll
    for (int rr = 0; rr < 8; ++rr) v4[rr] = s4[(pb ^ PH2(rr << 9)) >> 2];
  }
  __syncthreads();   // all LDS reads done; s reused for reduction below
  ry32<3>(v, SHC(3)); ry32<2>(v, SHC(4)); ry32<1>(v, SHC(5)); ry32<0>(v, SHC(6));

  // reg bits: r0=l7=q6, r1=l8=q5, r2=l9=q4, r3=l10=q3, r4=l11=q2
  float S = 0, aq6 = 0, aq5 = 0, aq4 = 0, aq3 = 0, aq2 = 0;
#pragma unroll
  for (int r = 0; r < 32; ++r) {
    float p = v[r] * v[r];
    S += p;
    aq6 += (r & 1)  ? -p : p;
    aq5 += (r & 2)  ? -p : p;
    aq4 += (r & 4)  ? -p : p;
    aq3 += (r & 8)  ? -p : p;
    aq2 += (r & 16) ? -p : p;
  }
  float a21[21];
  a21[6] = aq6; a21[5] = aq5; a21[4] = aq4; a21[3] = aq3; a21[2] = aq2;
  a21[20] = (tid & 1)   ? -S : S;  // l0 = g0  -> q20
  a21[19] = (tid & 2)   ? -S : S;  // l1 = g1  -> q19
  a21[18] = (tid & 4)   ? -S : S;  // l2 = g2  -> q18
  a21[17] = (tid & 8)   ? -S : S;  // l3 = g3  -> q17
  a21[16] = (tid & 16)  ? -S : S;  // l4 = g4  -> q16
  a21[15] = (tid & 32)  ? -S : S;  // l5 = g5  -> q15
  a21[7]  = (tid & 64)  ? -S : S;  // l6 = g13 -> q7
  a21[1]  = (tid & 128) ? -S : S;  // l12 = g19 -> q1
  a21[0]  = (tid & 256) ? -S : S;  // l13 = g20 -> q0
  a21[14] = (t & 1)  ? -S : S;     // g6  -> q14
  a21[13] = (t & 2)  ? -S : S;
  a21[12] = (t & 4)  ? -S : S;
  a21[11] = (t & 8)  ? -S : S;
  a21[10] = (t & 16) ? -S : S;
  a21[9]  = (t & 32) ? -S : S;
  a21[8]  = (t & 64) ? -S : S;     // g12 -> q8

  const int wv = tid >> 6;
#pragma unroll
  for (int q = 0; q < 21; ++q) {
    float val = a21[q];
    val += __shfl_down(val, 32);
    val += __shfl_down(val, 16);
    val += __shfl_down(val, 8);
    val += __shfl_down(val, 4);
    val += __shfl_down(val, 2);
    val += __shfl_down(val, 1);
    if (lane == 0) s[q * 8 + wv] = val;
  }
  __syncthreads();
  if (tid < NQ) {
    float sum = 0.f;
#pragma unroll
    for (int k = 0; k < 8; ++k) sum += s[tid * 8 + k];
    partial[blockIdx.x * NQ + tid] = sum;
  }
}

// ---------------- barrier state zero-init ----------------
__global__ void k_zero(unsigned* __restrict__ bars) {
  if (threadIdx.x < 8) bars[threadIdx.x] = 0u;
}

// ---------------- fused persistent kernel ----------------
__global__ __launch_bounds__(512, 4) void k_fused(const float* __restrict__ x,
                                                  const float* __restrict__ w,
                                                  unsigned long long stp,
                                                  float* __restrict__ partial,
                                                  float* __restrict__ out,
                                                  unsigned* __restrict__ bars) {
  __shared__ __align__(16) float s[16384];
  const int b = blockIdx.x >> 7;
  unsigned* bar = bars + 2 * b;      // per-batch barrier [cnt, gen]

  dL<true>(x, w + 0, stp, s);          gbar(bar);
  dH(w + 0, stp, s);                   gbar(bar);
  dL<false>(nullptr, w + 21, stp, s);  gbar(bar);
  dH(w + 21, stp, s);                  gbar(bar);
  dL<false>(nullptr, w + 42, stp, s);  gbar(bar);
  dHfin(w + 42, stp, partial, s);      gbar(bar);

  // batch-b reducer: first block of each batch
  if ((blockIdx.x & 127) == 0) {
    const int tid = threadIdx.x;
    const int q = tid >> 3, k8 = tid & 7;
    if (tid < 168) {
      float sum = 0.f;
#pragma unroll
      for (int i = 0; i < 16; ++i)
        sum += partial[((b << 7) + (k8 << 4) + i) * NQ + q];
      s[tid] = sum;
    }
    __syncthreads();
    if (tid < NQ) {
      float sum = 0.f;
#pragma unroll
      for (int k = 0; k < 8; ++k) sum += s[tid * 8 + k];
      out[b * NQ + tid] = sum;
    }
  }
}

extern "C" void kernel_launch(void* const* d_in, const int* in_sizes, int n_in,
                              void* d_out, int out_size, void* d_ws, size_t ws_size,
                              hipStream_t stream) {
  const float* x = (const float*)d_in[0];   // (4,21) f32
  const float* w = (const float*)d_in[1];   // (3,21) f32
  float* out = (float*)d_out;               // (4,21) f32
  unsigned long long stp = (unsigned long long)d_ws;                 // 16 MB fp16 state
  const size_t st_bytes = ((size_t)4 << 21) * 2;
  float* partial = (float*)((char*)d_ws + st_bytes);                 // 512*21 f32 = 43008 B
  unsigned* bars = (unsigned*)((char*)d_ws + st_bytes + 43008);      // 4 x {cnt,gen}
  if (ws_size < st_bytes + 43008 + 64) return;

  k_zero <<<1, dim3(64), 0, stream>>>(bars);
  k_fused<<<dim3(512), dim3(512), 0, stream>>>(x, w, stp, partial, out, bars);
}

// Round 7
// 346.507 us; speedup vs baseline: 1.8598x; 1.8598x over previous
//
#include <hip/hip_runtime.h>
#include <hip/hip_fp16.h>

// 21-qubit batched (B=4) state-vector simulator.
// R7: R6 fused persistent kernel with FIXED per-batch barrier:
//   - RELAXED spin polls (R6's per-poll ACQUIRE emitted buffer_inv -> L2
//     invalidate storm, the 670us pathology) + s_sleep between polls
//   - one release fence at arrival, one acquire fence at exit (per block)
//   - leader fences before publishing gen (formal HB chain)
//   - cnt/gen on separate cachelines, 128B per batch (no false sharing)
// Phase bodies identical to R5/R6 (verified, absmax 3e-5): fp16 global state,
// f32 LDS tiles, sigma-relayout consecutive-bit windows, b128 reads/b32 scatter.

#define NQ 21
#define SHC(q) __shfl(cv, (q)), __shfl(sv, (q))

__device__ constexpr int PH2(int slot) {
  int blk = slot >> 2;
  blk ^= ((blk >> 3) & 7) ^ ((blk >> 6) & 7);
  return (blk << 2) | (slot & 3);
}

template<int Q>
__device__ __forceinline__ void ry32(float* v, float c, float s) {
#pragma unroll
  for (int k = 0; k < 16; ++k) {
    int l0 = ((k >> Q) << (Q + 1)) | (k & ((1 << Q) - 1));
    int l1 = l0 | (1 << Q);
    float a0 = v[l0], a1 = v[l1];
    v[l0] = c * a0 - s * a1;
    v[l1] = s * a0 + c * a1;
  }
}

template<int C, int T>
__device__ __forceinline__ void cnot32(float* v) {
  constexpr int lo = (C < T) ? C : T;
  constexpr int hi = (C < T) ? T : C;
#pragma unroll
  for (int k = 0; k < 8; ++k) {
    int i1 = ((k >> lo) << (lo + 1)) | (k & ((1 << lo) - 1));
    int i2 = ((i1 >> hi) << (hi + 1)) | (i1 & ((1 << hi) - 1));
    int a = i2 | (1 << C);   // control = 1, target = 0
    int b = a | (1 << T);
    float tmp = v[a]; v[a] = v[b]; v[b] = tmp;
  }
}

// 4 amps (8B) fp16 <-> 4 f32 regs
__device__ __forceinline__ void ld4(const uint2* __restrict__ g, int idx, float* dst) {
  uint2 r = g[idx];
  __half2 h0 = *reinterpret_cast<__half2*>(&r.x);
  __half2 h1 = *reinterpret_cast<__half2*>(&r.y);
  float2 f0 = __half22float2(h0), f1 = __half22float2(h1);
  dst[0] = f0.x; dst[1] = f0.y; dst[2] = f1.x; dst[3] = f1.y;
}
__device__ __forceinline__ uint2 pk4(const float* src) {
  __half2 h0 = __floats2half2_rn(src[0], src[1]);
  __half2 h1 = __floats2half2_rn(src[2], src[3]);
  uint2 r;
  r.x = *reinterpret_cast<unsigned int*>(&h0);
  r.y = *reinterpret_cast<unsigned int*>(&h1);
  return r;
}

#define A1 (tid | (rr << 9))
#define GH(l4) (((l4) & 0xF) | (t << 4) | (((l4) >> 4) << 11))

// ---------------- per-batch global barrier (128 blocks) ----------------
// bar[0] = cnt (line 0), bar[16] = gen (line 1). Self-resetting; gen monotonic.
__device__ __forceinline__ void gbar(unsigned* bar) {
  __syncthreads();
  if (threadIdx.x == 0) {
    __threadfence();   // release: write back this block's phase stores
    unsigned g = __hip_atomic_load(bar + 16, __ATOMIC_RELAXED, __HIP_MEMORY_SCOPE_AGENT);
    if (__hip_atomic_fetch_add(bar, 1u, __ATOMIC_RELAXED, __HIP_MEMORY_SCOPE_AGENT) == 127u) {
      __threadfence();  // acquire all arrivals' data before publishing gen
      __hip_atomic_store(bar, 0u, __ATOMIC_RELAXED, __HIP_MEMORY_SCOPE_AGENT);
      __hip_atomic_fetch_add(bar + 16, 1u, __ATOMIC_RELEASE, __HIP_MEMORY_SCOPE_AGENT);
    } else {
      while (__hip_atomic_load(bar + 16, __ATOMIC_RELAXED, __HIP_MEMORY_SCOPE_AGENT) == g)
        __builtin_amdgcn_s_sleep(16);
      __threadfence(); // acquire: invalidate stale lines before next phase reads
    }
  }
  __syncthreads();
}

// ---------------- L pass body (R5-verified) ----------------
template<bool INIT>
__device__ __forceinline__ void dL(const float* __restrict__ x,
                                   const float* __restrict__ w,
                                   unsigned long long stp, float* __restrict__ s) {
  float4* s4 = reinterpret_cast<float4*>(s);
  const int tid = threadIdx.x, lane = tid & 63;
  const int b = blockIdx.x >> 7, t = blockIdx.x & 127;
  float cv = 1.f, sv = 0.f;
  if (lane < NQ) sincosf(0.5f * w[lane], &sv, &cv);
  uint2* g2 = reinterpret_cast<uint2*>(stp) + ((size_t)b << 19) + ((size_t)t << 12);
  float v[32];
  float4* v4 = reinterpret_cast<float4*>(v);

  // ---- S1: window {0,1,11,12,13}: C(13,12),(12,11); RY 13(q7),12(q8) ----
  if (INIT) {
    float cx = 1.f, sx = 0.f;
    if (lane < NQ) sincosf(0.5f * x[b * NQ + lane], &sx, &cx);
    float Qp = 1.f;
#pragma unroll
    for (int i = 0; i < 9; ++i) {            // tid bit i -> g(2+i) -> qubit 18-i
      float cq = __shfl(cx, 18 - i), sq = __shfl(sx, 18 - i);
      Qp *= ((tid >> i) & 1) ? sq : cq;
    }
    float hfac[2];
#pragma unroll
    for (int bb = 0; bb < 2; ++bb) {         // g13 = bb, h = g[13..20]
      int h = (t << 1) | bb;
      int h0 = h ^ (h >> 1);                 // pre-image of high chain
      float p = 1.f;
#pragma unroll
      for (int j = 0; j < 8; ++j) {          // h0 bit j -> g(13+j) -> qubit 7-j
        float cq = __shfl(cx, 7 - j), sq = __shfl(sx, 7 - j);
        p *= ((h0 >> j) & 1) ? sq : cq;
      }
      hfac[bb] = p;
    }
    float c20 = __shfl(cx, 20), s20 = __shfl(sx, 20);
    float c19 = __shfl(cx, 19), s19 = __shfl(sx, 19);
    float c9  = __shfl(cx, 9),  s9  = __shfl(sx, 9);
    float c8  = __shfl(cx, 8),  s8  = __shfl(sx, 8);
    float w0t[4], w1t[4];
#pragma unroll
    for (int i = 0; i < 4; ++i) {
      w0t[i] = ((i & 1) ? s20 : c20) * ((i & 2) ? s19 : c19);  // amp bits 0,1
      w1t[i] = ((i & 1) ? s9  : c9 ) * ((i & 2) ? s8  : c8 );  // amp bits 11,12
    }
#pragma unroll
    for (int r = 0; r < 32; ++r)
      v[r] = hfac[(r >> 4) & 1] * w1t[(r >> 2) & 3] * w0t[r & 3] * Qp;
  } else {
#pragma unroll
    for (int rr = 0; rr < 8; ++rr) ld4(g2, A1, v + 4 * rr);
  }
  cnot32<4, 3>(v); cnot32<3, 2>(v);
  ry32<4>(v, SHC(7)); ry32<3>(v, SHC(8));
  {
    const int pb = PH2(((tid & 31) << 2) | ((tid >> 5) & 3) | (((tid >> 7) & 3) << 9));
#pragma unroll
    for (int r = 0; r < 32; ++r)
      s[pb ^ PH2(((r & 3) << 7) | ((r >> 2) << 11))] = v[r];
  }
  __syncthreads();

  // ---- S2: window {7..11}: C(11,10),(10,9),(9,8),(8,7); RY 11..8 (q9..q12) ----
  {
    const int pb = PH2(((tid & 3) << 7) | (tid & 0x7C) | ((tid >> 7) << 12));
#pragma unroll
    for (int rr = 0; rr < 8; ++rr) v4[rr] = s4[(pb ^ PH2(rr << 9)) >> 2];
  }
  cnot32<4, 3>(v); cnot32<3, 2>(v); cnot32<2, 1>(v); cnot32<1, 0>(v);
  ry32<4>(v, SHC(9)); ry32<3>(v, SHC(10)); ry32<2>(v, SHC(11)); ry32<1>(v, SHC(12));
  __syncthreads();
  {
    const int pb = PH2(((tid >> 3) & 3) | (tid & 4) | ((tid & 3) << 3) |
                       (tid & 0x60) | ((tid >> 7) << 12));
#pragma unroll
    for (int r = 0; r < 32; ++r) s[pb ^ PH2(r << 7)] = v[r];
  }
  __syncthreads();

  // ---- S3: window {3..7}: C(7,6),(6,5),(5,4),(4,3); RY 7..4 (q13..q16) ----
  {
    const int pb = PH2(((tid & 3) << 3) | (tid & 4) | ((tid >> 3) << 8));
#pragma unroll
    for (int rr = 0; rr < 8; ++rr) v4[rr] = s4[(pb ^ PH2(rr << 5)) >> 2];
  }
  cnot32<4, 3>(v); cnot32<3, 2>(v); cnot32<2, 1>(v); cnot32<1, 0>(v);
  ry32<4>(v, SHC(13)); ry32<3>(v, SHC(14)); ry32<2>(v, SHC(15)); ry32<1>(v, SHC(16));
  __syncthreads();
  {
    const int pb = PH2((tid & 7) | ((tid >> 3) << 8));
#pragma unroll
    for (int r = 0; r < 32; ++r) s[pb ^ PH2(r << 3)] = v[r];
  }
  __syncthreads();

  // ---- S4: window {0..4}: C(3,2),(2,1),(1,0); RY 3,2,1 (q17,q18,q19); store ----
  {
    const int pb = PH2(tid << 5);
#pragma unroll
    for (int rr = 0; rr < 8; ++rr) v4[rr] = s4[(pb ^ PH2(rr << 2)) >> 2];
  }
  cnot32<3, 2>(v); cnot32<2, 1>(v); cnot32<1, 0>(v);
  ry32<3>(v, SHC(17)); ry32<2>(v, SHC(18)); ry32<1>(v, SHC(19));
  {
    uint4* g4o = reinterpret_cast<uint4*>(g2);
#pragma unroll
    for (int rr = 0; rr < 8; rr += 2) {
      uint2 lo = pk4(v + 4 * rr), hi = pk4(v + 4 * rr + 4);
      uint4 o; o.x = lo.x; o.y = lo.y; o.z = hi.x; o.w = hi.y;
      g4o[((rr | (tid << 3)) >> 1)] = o;
    }
  }
}

// ---------------- H pass body (R5-verified) ----------------
__device__ __forceinline__ void dH(const float* __restrict__ w,
                                   unsigned long long stp, float* __restrict__ s) {
  float4* s4 = reinterpret_cast<float4*>(s);
  const int tid = threadIdx.x, lane = tid & 63;
  const int b = blockIdx.x >> 7, t = blockIdx.x & 127;
  float cv = 1.f, sv = 0.f;
  if (lane < NQ) sincosf(0.5f * w[lane], &sv, &cv);
  uint2* gb = reinterpret_cast<uint2*>(stp) + ((size_t)b << 19);
  float v[32];
  float4* v4 = reinterpret_cast<float4*>(v);

  // ---- HS1: wrap C(l0,l13); RY l0(q20),l13(q0),l12(q1),l11(q2); chain x2 ----
#pragma unroll
  for (int rr = 0; rr < 8; ++rr) ld4(gb, GH(A1), v + 4 * rr);
  cnot32<0, 4>(v);
  ry32<0>(v, SHC(20)); ry32<4>(v, SHC(0)); ry32<3>(v, SHC(1)); ry32<2>(v, SHC(2));
  cnot32<4, 3>(v); cnot32<3, 2>(v);
  {
    const int pb = PH2(((tid & 31) << 2) | ((tid >> 5) & 3) | (((tid >> 7) & 3) << 9));
#pragma unroll
    for (int r = 0; r < 32; ++r)
      s[pb ^ PH2(((r & 3) << 7) | ((r >> 2) << 11))] = v[r];
  }
  __syncthreads();

  // ---- HS2: RY l10(q3),l9(q4),l8(q5),l7(q6); chain C x4 ----
  {
    const int pb = PH2(((tid & 3) << 7) | (tid & 0x7C) | ((tid >> 7) << 12));
#pragma unroll
    for (int rr = 0; rr < 8; ++rr) v4[rr] = s4[(pb ^ PH2(rr << 9)) >> 2];
  }
  ry32<3>(v, SHC(3)); ry32<2>(v, SHC(4)); ry32<1>(v, SHC(5)); ry32<0>(v, SHC(6));
  cnot32<4, 3>(v); cnot32<3, 2>(v); cnot32<2, 1>(v); cnot32<1, 0>(v);
  __syncthreads();
  {
    const int pb = PH2((tid & 127) | ((tid >> 7) << 12));
#pragma unroll
    for (int r = 0; r < 32; ++r) s[pb ^ PH2(r << 7)] = v[r];
  }
  __syncthreads();

  // ---- HS3: window {l0,l1,l5,l6,l7}: chain C(l7,l6); store ----
  {
    const int pb = PH2(((tid & 7) << 2) | ((tid >> 3) << 8));
#pragma unroll
    for (int rr = 0; rr < 8; ++rr) v4[rr] = s4[(pb ^ PH2(rr << 5)) >> 2];
  }
  cnot32<4, 3>(v);
#pragma unroll
  for (int rr = 0; rr < 8; ++rr) {
    int l4 = (tid & 7) | (rr << 3) | ((tid >> 3) << 6);
    gb[GH(l4)] = pk4(v + 4 * rr);
  }
}

// ---------------- final H pass + measurement body (R5-verified) ----------------
__device__ __forceinline__ void dHfin(const float* __restrict__ w,
                                      unsigned long long stp,
                                      float* __restrict__ partial,
                                      float* __restrict__ s) {
  float4* s4 = reinterpret_cast<float4*>(s);
  const int tid = threadIdx.x, lane = tid & 63;
  const int b = blockIdx.x >> 7, t = blockIdx.x & 127;
  float cv = 1.f, sv = 0.f;
  if (lane < NQ) sincosf(0.5f * w[lane], &sv, &cv);
  const uint2* gb = reinterpret_cast<const uint2*>(stp) + ((size_t)b << 19);
  float v[32];
  float4* v4 = reinterpret_cast<float4*>(v);

  // ---- HS1f: wrap; RY l0,l13,l12,l11 ----
#pragma unroll
  for (int rr = 0; rr < 8; ++rr) ld4(gb, GH(A1), v + 4 * rr);
  cnot32<0, 4>(v);
  ry32<0>(v, SHC(20)); ry32<4>(v, SHC(0)); ry32<3>(v, SHC(1)); ry32<2>(v, SHC(2));
  {
    const int pb = PH2(((tid & 31) << 2) | ((tid >> 5) & 3) | (((tid >> 7) & 3) << 9));
#pragma unroll
    for (int r = 0; r < 32; ++r)
      s[pb ^ PH2(((r & 3) << 7) | ((r >> 2) << 11))] = v[r];
  }
  __syncthreads();

  // ---- HS2f: window {l7..l11}: RY l10(q3),l9(q4),l8(q5),l7(q6); measure ----
  {
    const int pb = PH2(((tid & 3) << 7) | (tid & 0x7C) | ((tid >> 7) << 12));
#pragma unroll
    for (int rr = 0; rr < 8; ++rr) v4[rr] = s4[(pb ^ PH2(rr << 9)) >> 2];
  }
  __syncthreads();   // all LDS reads done; s reused for reduction below
  ry32<3>(v, SHC(3)); ry32<2>(v, SHC(4)); ry32<1>(v, SHC(5)); ry32<0>(v, SHC(6));

  // reg bits: r0=l7=q6, r1=l8=q5, r2=l9=q4, r3=l10=q3, r4=l11=q2
  float S = 0, aq6 = 0, aq5 = 0, aq4 = 0, aq3 = 0, aq2 = 0;
#pragma unroll
  for (int r = 0; r < 32; ++r) {
    float p = v[r] * v[r];
    S += p;
    aq6 += (r & 1)  ? -p : p;
    aq5 += (r & 2)  ? -p : p;
    aq4 += (r & 4)  ? -p : p;
    aq3 += (r & 8)  ? -p : p;
    aq2 += (r & 16) ? -p : p;
  }
  float a21[21];
  a21[6] = aq6; a21[5] = aq5; a21[4] = aq4; a21[3] = aq3; a21[2] = aq2;
  a21[20] = (tid & 1)   ? -S : S;  // l0 = g0  -> q20
  a21[19] = (tid & 2)   ? -S : S;  // l1 = g1  -> q19
  a21[18] = (tid & 4)   ? -S : S;  // l2 = g2  -> q18
  a21[17] = (tid & 8)   ? -S : S;  // l3 = g3  -> q17
  a21[16] = (tid & 16)  ? -S : S;  // l4 = g4  -> q16
  a21[15] = (tid & 32)  ? -S : S;  // l5 = g5  -> q15
  a21[7]  = (tid & 64)  ? -S : S;  // l6 = g13 -> q7
  a21[1]  = (tid & 128) ? -S : S;  // l12 = g19 -> q1
  a21[0]  = (tid & 256) ? -S : S;  // l13 = g20 -> q0
  a21[14] = (t & 1)  ? -S : S;     // g6  -> q14
  a21[13] = (t & 2)  ? -S : S;
  a21[12] = (t & 4)  ? -S : S;
  a21[11] = (t & 8)  ? -S : S;
  a21[10] = (t & 16) ? -S : S;
  a21[9]  = (t & 32) ? -S : S;
  a21[8]  = (t & 64) ? -S : S;     // g12 -> q8

  const int wv = tid >> 6;
#pragma unroll
  for (int q = 0; q < 21; ++q) {
    float val = a21[q];
    val += __shfl_down(val, 32);
    val += __shfl_down(val, 16);
    val += __shfl_down(val, 8);
    val += __shfl_down(val, 4);
    val += __shfl_down(val, 2);
    val += __shfl_down(val, 1);
    if (lane == 0) s[q * 8 + wv] = val;
  }
  __syncthreads();
  if (tid < NQ) {
    float sum = 0.f;
#pragma unroll
    for (int k = 0; k < 8; ++k) sum += s[tid * 8 + k];
    partial[blockIdx.x * NQ + tid] = sum;
  }
}

// ---------------- barrier state zero-init ----------------
__global__ void k_zero(unsigned* __restrict__ bars) {
  if (threadIdx.x < 128) bars[threadIdx.x] = 0u;
}

// ---------------- fused persistent kernel ----------------
__global__ __launch_bounds__(512, 4) void k_fused(const float* __restrict__ x,
                                                  const float* __restrict__ w,
                                                  unsigned long long stp,
                                                  float* __restrict__ partial,
                                                  float* __restrict__ out,
                                                  unsigned* __restrict__ bars) {
  __shared__ __align__(16) float s[16384];
  const int b = blockIdx.x >> 7;
  unsigned* bar = bars + 32 * b;     // 128B per batch: cnt = bar[0], gen = bar[16]

  dL<true>(x, w + 0, stp, s);          gbar(bar);
  dH(w + 0, stp, s);                   gbar(bar);
  dL<false>(nullptr, w + 21, stp, s);  gbar(bar);
  dH(w + 21, stp, s);                  gbar(bar);
  dL<false>(nullptr, w + 42, stp, s);  gbar(bar);
  dHfin(w + 42, stp, partial, s);      gbar(bar);

  // batch-b reducer: first block of each batch
  if ((blockIdx.x & 127) == 0) {
    const int tid = threadIdx.x;
    const int q = tid >> 3, k8 = tid & 7;
    if (tid < 168) {
      float sum = 0.f;
#pragma unroll
      for (int i = 0; i < 16; ++i)
        sum += partial[((b << 7) + (k8 << 4) + i) * NQ + q];
      s[tid] = sum;
    }
    __syncthreads();
    if (tid < NQ) {
      float sum = 0.f;
#pragma unroll
      for (int k = 0; k < 8; ++k) sum += s[tid * 8 + k];
      out[b * NQ + tid] = sum;
    }
  }
}

extern "C" void kernel_launch(void* const* d_in, const int* in_sizes, int n_in,
                              void* d_out, int out_size, void* d_ws, size_t ws_size,
                              hipStream_t stream) {
  const float* x = (const float*)d_in[0];   // (4,21) f32
  const float* w = (const float*)d_in[1];   // (3,21) f32
  float* out = (float*)d_out;               // (4,21) f32
  unsigned long long stp = (unsigned long long)d_ws;                 // 16 MB fp16 state
  const size_t st_bytes = ((size_t)4 << 21) * 2;
  float* partial = (float*)((char*)d_ws + st_bytes);                 // 512*21 f32 = 43008 B
  unsigned* bars = (unsigned*)((char*)d_ws + st_bytes + 43008);      // 4 x 128 B
  if (ws_size < st_bytes + 43008 + 512) return;

  k_zero <<<1, dim3(128), 0, stream>>>(bars);
  k_fused<<<dim3(512), dim3(512), 0, stream>>>(x, w, stp, partial, out, bars);
}

// Round 8
// 95.210 us; speedup vs baseline: 6.7684x; 3.6394x over previous
//
#include <hip/hip_runtime.h>
#include <hip/hip_fp16.h>

// 21-qubit batched (B=4) state-vector simulator, 6 split passes + reduce (R5
// structure). R8: conflict-free LDS layouts — each inter-sweep layout's low
// slot bits are chosen from (writer window ∩ reader window) so writes become
// paired b64 / quad b128 stores (16/8 instrs vs 32 b32, ~2-way banks vs 4-way).
// Gate v-bit mappings re-derived per sweep. XCD batch affinity: batch =
// (bid&7)>>1 keeps each batch's 4MB fp16 state on one XCD pair's L2.
// fp16 global state, f32 LDS tiles, qubit q <-> g-bit (20-q).

#define NQ 21
#define SHC(q) __shfl(cv, (q)), __shfl(sv, (q))

__device__ __forceinline__ int PH2B(int blk) {        // granule swizzle
  return blk ^ ((blk >> 3) & 7) ^ ((blk >> 6) & 7);
}

template<int Q>
__device__ __forceinline__ void ry32(float* v, float c, float s) {
#pragma unroll
  for (int k = 0; k < 16; ++k) {
    int l0 = ((k >> Q) << (Q + 1)) | (k & ((1 << Q) - 1));
    int l1 = l0 | (1 << Q);
    float a0 = v[l0], a1 = v[l1];
    v[l0] = c * a0 - s * a1;
    v[l1] = s * a0 + c * a1;
  }
}

template<int C, int T>
__device__ __forceinline__ void cnot32(float* v) {
  constexpr int lo = (C < T) ? C : T;
  constexpr int hi = (C < T) ? T : C;
#pragma unroll
  for (int k = 0; k < 8; ++k) {
    int i1 = ((k >> lo) << (lo + 1)) | (k & ((1 << lo) - 1));
    int i2 = ((i1 >> hi) << (hi + 1)) | (i1 & ((1 << hi) - 1));
    int a = i2 | (1 << C);
    int b = a | (1 << T);
    float tmp = v[a]; v[a] = v[b]; v[b] = tmp;
  }
}

__device__ __forceinline__ void ld4(const uint2* __restrict__ g, int idx, float* dst) {
  uint2 r = g[idx];
  __half2 h0 = *reinterpret_cast<__half2*>(&r.x);
  __half2 h1 = *reinterpret_cast<__half2*>(&r.y);
  float2 f0 = __half22float2(h0), f1 = __half22float2(h1);
  dst[0] = f0.x; dst[1] = f0.y; dst[2] = f1.x; dst[3] = f1.y;
}
__device__ __forceinline__ unsigned pkh(float a, float b) {
  __half2 h = __floats2half2_rn(a, b);
  return *reinterpret_cast<unsigned*>(&h);
}

#define A1 (tid | (rr << 9))
#define GH(l4) (((l4) & 0xF) | (t << 4) | (((l4) >> 4) << 11))

// sigma2-style write (S1/HS1): pairs over v-bit2; slot: s0=w2bit, s1=tid5,
// s2..6=tid0..4, s7,8=r0,r1, s9..11=tid6..8, s12,13=r3,r4.
#define WR_SIGMA2(s, v)                                                        \
  {                                                                            \
    const int pbs = (((tid >> 5) & 1) << 1) | ((tid & 31) << 2) |              \
                    (((tid >> 6) & 7) << 9);                                   \
    _Pragma("unroll") for (int i = 0; i < 16; ++i) {                           \
      int r = (i & 3) | ((i >> 2) << 3);                                       \
      int sl = pbs ^ (((i & 3) << 7) | ((i >> 2) << 12));                      \
      int a = (PH2B(sl >> 2) << 2) | (sl & 3);                                 \
      float2 o; o.x = (v)[r]; o.y = (v)[r | 4];                                \
      *reinterpret_cast<float2*>((s) + a) = o;                                 \
    }                                                                          \
  }

// sigma2-style read (S2/HS2): v0=w-bit at s0, v1=bit at s1, v2..4=rr (blk7..9)
#define RD_SIGMA2(s4, v4)                                                      \
  {                                                                            \
    const int pbb = (tid & 31) | (((tid >> 5) & 3) << 5) |                     \
                    (((tid >> 7) & 3) << 10);                                  \
    _Pragma("unroll") for (int rr = 0; rr < 8; ++rr)                           \
      (v4)[rr] = (s4)[PH2B(pbb ^ (rr << 7))];                                  \
  }

// ---------------- L pass: tile = bits 0..13, t = bits 14..20 ----------------
template<bool INIT>
__global__ __launch_bounds__(512, 4) void k_L(const float* __restrict__ x,
                                              const float* __restrict__ w,
                                              unsigned long long stp) {
  __shared__ __align__(16) float s[16384];
  float4* s4 = reinterpret_cast<float4*>(s);
  const int tid = threadIdx.x, lane = tid & 63;
  const int bid = blockIdx.x;
  const int b = (bid & 7) >> 1;                       // XCD-pair affinity
  const int t = ((bid >> 3) << 1) | (bid & 1);
  float cv = 1.f, sv = 0.f;
  if (lane < NQ) sincosf(0.5f * w[lane], &sv, &cv);
  uint2* g2 = reinterpret_cast<uint2*>(stp) + ((size_t)b << 19) + ((size_t)t << 12);
  float v[32];
  float4* v4 = reinterpret_cast<float4*>(v);

  // ---- S1: v = {amp0,amp1 | rr=amp11,12,13}: C(13,12),(12,11); RY q7,q8 ----
  if (INIT) {
    float cx = 1.f, sx = 0.f;
    if (lane < NQ) sincosf(0.5f * x[b * NQ + lane], &sx, &cx);
    float Qp = 1.f;
#pragma unroll
    for (int i = 0; i < 9; ++i) {            // tid bit i -> g(2+i) -> qubit 18-i
      float cq = __shfl(cx, 18 - i), sq = __shfl(sx, 18 - i);
      Qp *= ((tid >> i) & 1) ? sq : cq;
    }
    float hfac[2];
#pragma unroll
    for (int bb = 0; bb < 2; ++bb) {         // g13 = bb, h = g[13..20]
      int h = (t << 1) | bb;
      int h0 = h ^ (h >> 1);                 // pre-image of high chain
      float p = 1.f;
#pragma unroll
      for (int j = 0; j < 8; ++j) {
        float cq = __shfl(cx, 7 - j), sq = __shfl(sx, 7 - j);
        p *= ((h0 >> j) & 1) ? sq : cq;
      }
      hfac[bb] = p;
    }
    float c20 = __shfl(cx, 20), s20 = __shfl(sx, 20);
    float c19 = __shfl(cx, 19), s19 = __shfl(sx, 19);
    float c9  = __shfl(cx, 9),  s9  = __shfl(sx, 9);
    float c8  = __shfl(cx, 8),  s8  = __shfl(sx, 8);
    float w0t[4], w1t[4];
#pragma unroll
    for (int i = 0; i < 4; ++i) {
      w0t[i] = ((i & 1) ? s20 : c20) * ((i & 2) ? s19 : c19);  // amps 0,1
      w1t[i] = ((i & 1) ? s9  : c9 ) * ((i & 2) ? s8  : c8 );  // amps 11,12
    }
#pragma unroll
    for (int r = 0; r < 32; ++r)
      v[r] = hfac[(r >> 4) & 1] * w1t[(r >> 2) & 3] * w0t[r & 3] * Qp;
  } else {
#pragma unroll
    for (int rr = 0; rr < 8; ++rr) ld4(g2, A1, v + 4 * rr);
  }
  cnot32<4, 3>(v); cnot32<3, 2>(v);
  ry32<4>(v, SHC(7)); ry32<3>(v, SHC(8));
  WR_SIGMA2(s, v);                           // s0=amp11
  __syncthreads();

  // ---- S2: v = {amp11,amp7 | rr=amp8,9,10}: C(11,10),(10,9),(9,8),(8,7) ----
  RD_SIGMA2(s4, v4);
  cnot32<0, 4>(v); cnot32<4, 3>(v); cnot32<3, 2>(v); cnot32<2, 1>(v);
  ry32<0>(v, SHC(9)); ry32<4>(v, SHC(10)); ry32<3>(v, SHC(11)); ry32<2>(v, SHC(12));
  __syncthreads();
  {
    // sigma3: s0=amp7(pair), s1=amp3, s2=amp4, s3=amp5, s4=amp6, s5=amp2,
    // s6=amp1, s7=amp0, s8..10=amp8..10, s11=amp11, s12,13=amp12,13
    const int pbs = (tid & 0x1E) | ((tid & 1) << 5) | (tid & 0x40) |
                    (((tid >> 5) & 1) << 7) | ((tid >> 7) << 12);
#pragma unroll
    for (int i = 0; i < 16; ++i) {
      int r = (i & 1) | ((i >> 1) << 2);
      int sl = pbs ^ ((((i >> 1) & 7) << 8) | ((i & 1) << 11));
      int a = (PH2B(sl >> 2) << 2) | (sl & 3);
      float2 o; o.x = v[r]; o.y = v[r | 2];
      *reinterpret_cast<float2*>(s + a) = o;
    }
  }
  __syncthreads();

  // ---- S3: v = {amp7,amp3 | rr=amp4,5,6}: C(7,6),(6,5),(5,4),(4,3) ----
  {
    const int pbb = ((tid & 7) << 3) | (((tid >> 3) & 7) << 6) | (((tid >> 6) & 7) << 9);
#pragma unroll
    for (int rr = 0; rr < 8; ++rr) v4[rr] = s4[PH2B(pbb | rr)];
  }
  cnot32<0, 4>(v); cnot32<4, 3>(v); cnot32<3, 2>(v); cnot32<2, 1>(v);
  ry32<0>(v, SHC(13)); ry32<4>(v, SHC(14)); ry32<3>(v, SHC(15)); ry32<2>(v, SHC(16));
  __syncthreads();
  {
    // identity'': s0=amp3, s1=amp4 (quads), s2=amp0, s3=amp1, s4=amp2,
    // s5=amp5, s6=amp6, s7=amp7, s8..13=amp8..13
    const int pbs = (((tid >> 2) & 1) << 2) | (((tid >> 1) & 1) << 3) |
                    ((tid & 1) << 4) | (((tid >> 3) & 7) << 8) |
                    (((tid >> 6) & 7) << 11);
#pragma unroll
    for (int i = 0; i < 8; ++i) {
      int r = (i & 1) | ((i >> 1) << 3);
      int sl = pbs ^ ((((i >> 1) & 1) << 5) | (((i >> 2) & 1) << 6) | ((i & 1) << 7));
      int a = PH2B(sl >> 2) << 2;
      float4 o; o.x = v[r]; o.y = v[r | 2]; o.z = v[r | 4]; o.w = v[r | 6];
      *reinterpret_cast<float4*>(s + a) = o;
    }
  }
  __syncthreads();

  // ---- S4: v = {amp3,amp4 | rr=amp0,1,2}: C(3,2),(2,1),(1,0); RY q17..q19 ----
  {
    const int pbb = tid << 3;
#pragma unroll
    for (int rr = 0; rr < 8; ++rr) v4[rr] = s4[PH2B(pbb | rr)];
  }
  cnot32<0, 4>(v); cnot32<4, 3>(v); cnot32<3, 2>(v);
  ry32<0>(v, SHC(17)); ry32<4>(v, SHC(18)); ry32<3>(v, SHC(19));
  {
    uint4* g4o = reinterpret_cast<uint4*>(g2);
#pragma unroll
    for (int i = 0; i < 4; ++i) {            // i = {a3, a4}
      int c = (i & 1) | ((i >> 1) << 1);
      uint4 o;
      o.x = pkh(v[c], v[c + 4]);   o.y = pkh(v[c + 8], v[c + 12]);
      o.z = pkh(v[c + 16], v[c + 20]); o.w = pkh(v[c + 24], v[c + 28]);
      g4o[(i & 1) | ((i >> 1) << 1) | (tid << 2)] = o;
    }
  }
}

// ---------------- H pass: tile = {g0..g5, g13..g20} (l0..l5, l6..l13) ----------------
__global__ __launch_bounds__(512, 4) void k_H(const float* __restrict__ w,
                                              unsigned long long stp) {
  __shared__ __align__(16) float s[16384];
  float4* s4 = reinterpret_cast<float4*>(s);
  const int tid = threadIdx.x, lane = tid & 63;
  const int bid = blockIdx.x;
  const int b = (bid & 7) >> 1;
  const int t = ((bid >> 3) << 1) | (bid & 1);
  float cv = 1.f, sv = 0.f;
  if (lane < NQ) sincosf(0.5f * w[lane], &sv, &cv);
  uint2* gb = reinterpret_cast<uint2*>(stp) + ((size_t)b << 19);
  float v[32];
  float4* v4 = reinterpret_cast<float4*>(v);

  // ---- HS1: v = {l0,l1 | rr=l11,l12,l13}: wrap C(l0,l13); RY q20,q0,q1,q2;
  //      next-layer chain C(l13,l12),(l12,l11) ----
#pragma unroll
  for (int rr = 0; rr < 8; ++rr) ld4(gb, GH(A1), v + 4 * rr);
  cnot32<0, 4>(v);
  ry32<0>(v, SHC(20)); ry32<4>(v, SHC(0)); ry32<3>(v, SHC(1)); ry32<2>(v, SHC(2));
  cnot32<4, 3>(v); cnot32<3, 2>(v);
  WR_SIGMA2(s, v);                           // s0=l11
  __syncthreads();

  // ---- HS2: v = {l11,l7 | rr=l8,l9,l10}: RY q3..q6; chain C(l11,l10)..(l8,l7) ----
  RD_SIGMA2(s4, v4);
  ry32<4>(v, SHC(3)); ry32<3>(v, SHC(4)); ry32<2>(v, SHC(5)); ry32<1>(v, SHC(6));
  cnot32<0, 4>(v); cnot32<4, 3>(v); cnot32<3, 2>(v); cnot32<2, 1>(v);
  __syncthreads();
  {
    // sigma3H: s0=l7(pair), s1=l5, s2=l0, s3=l1, s4=l6, s5=l2, s6=l3, s7=l4,
    // s8..10=l8..10, s11=l11, s12,13=l12,13
    const int pbs = (((tid >> 3) & 1) << 1) | (((tid >> 5) & 1) << 2) |
                    (((tid >> 6) & 1) << 3) | (tid & 16) | ((tid & 1) << 5) |
                    (((tid >> 1) & 1) << 6) | (((tid >> 2) & 1) << 7) |
                    ((tid >> 7) << 12);
#pragma unroll
    for (int i = 0; i < 16; ++i) {
      int r = (i & 1) | ((i >> 1) << 2);
      int sl = pbs ^ ((((i >> 1) & 7) << 8) | ((i & 1) << 11));
      int a = (PH2B(sl >> 2) << 2) | (sl & 3);
      float2 o; o.x = v[r]; o.y = v[r | 2];
      *reinterpret_cast<float2*>(s + a) = o;
    }
  }
  __syncthreads();

  // ---- HS3: v = {l7,l5 | rr=l0,l1,l6}: chain C(l7,l6); store ----
  {
    const int pbb = ((tid & 7) << 3) | (((tid >> 3) & 7) << 6) | (((tid >> 6) & 7) << 9);
#pragma unroll
    for (int rr = 0; rr < 8; ++rr) v4[rr] = s4[PH2B(pbb | rr)];
  }
  cnot32<0, 4>(v);
#pragma unroll
  for (int i = 0; i < 8; ++i) {              // i = {r0(l7), r1(l5), r4(l6)}
    int r0 = i & 1, r1 = (i >> 1) & 1, rh = (i >> 2) & 1;
    int c = r0 | (r1 << 1) | (rh << 4);
    int gidx = (tid & 7) | (r1 << 3) | (t << 4) |
               ((rh | (r0 << 1) | (((tid >> 3) & 0x3F) << 2)) << 11);
    uint2 o; o.x = pkh(v[c], v[c + 4]); o.y = pkh(v[c + 8], v[c + 12]);
    gb[gidx] = o;
  }
}

// ---------------- final H pass + measurement ----------------
__global__ __launch_bounds__(512, 4) void k_Hfin(const float* __restrict__ w,
                                                 unsigned long long stp,
                                                 float* __restrict__ partial) {
  __shared__ __align__(16) float s[16384];
  float4* s4 = reinterpret_cast<float4*>(s);
  const int tid = threadIdx.x, lane = tid & 63;
  const int bid = blockIdx.x;
  const int b = (bid & 7) >> 1;
  const int t = ((bid >> 3) << 1) | (bid & 1);
  float cv = 1.f, sv = 0.f;
  if (lane < NQ) sincosf(0.5f * w[lane], &sv, &cv);
  const uint2* gb = reinterpret_cast<const uint2*>(stp) + ((size_t)b << 19);
  float v[32];
  float4* v4 = reinterpret_cast<float4*>(v);

  // ---- HS1f: wrap; RY q20,q0,q1,q2 ----
#pragma unroll
  for (int rr = 0; rr < 8; ++rr) ld4(gb, GH(A1), v + 4 * rr);
  cnot32<0, 4>(v);
  ry32<0>(v, SHC(20)); ry32<4>(v, SHC(0)); ry32<3>(v, SHC(1)); ry32<2>(v, SHC(2));
  WR_SIGMA2(s, v);
  __syncthreads();

  // ---- HS2f: v = {l11,l7 | rr=l8,l9,l10}: RY q3..q6; measure ----
  RD_SIGMA2(s4, v4);
  __syncthreads();   // all LDS reads done; s reused for reduction below
  ry32<4>(v, SHC(3)); ry32<3>(v, SHC(4)); ry32<2>(v, SHC(5)); ry32<1>(v, SHC(6));

  // v bits: 0=l11(q2), 1=l7(q6), 2=l8(q5), 3=l9(q4), 4=l10(q3)
  float S = 0, aq2 = 0, aq6 = 0, aq5 = 0, aq4 = 0, aq3 = 0;
#pragma unroll
  for (int r = 0; r < 32; ++r) {
    float p = v[r] * v[r];
    S += p;
    aq2 += (r & 1)  ? -p : p;
    aq6 += (r & 2)  ? -p : p;
    aq5 += (r & 4)  ? -p : p;
    aq4 += (r & 8)  ? -p : p;
    aq3 += (r & 16) ? -p : p;
  }
  float a21[21];
  a21[2] = aq2; a21[6] = aq6; a21[5] = aq5; a21[4] = aq4; a21[3] = aq3;
  // thread bits: tid0..4 = l2..l6 -> q18,q17,q16,q15,q7; tid5,6 = l0,l1 ->
  // q20,q19; tid7,8 = l12,l13 -> q1,q0
  a21[18] = (tid & 1)   ? -S : S;
  a21[17] = (tid & 2)   ? -S : S;
  a21[16] = (tid & 4)   ? -S : S;
  a21[15] = (tid & 8)   ? -S : S;
  a21[7]  = (tid & 16)  ? -S : S;
  a21[20] = (tid & 32)  ? -S : S;
  a21[19] = (tid & 64)  ? -S : S;
  a21[1]  = (tid & 128) ? -S : S;
  a21[0]  = (tid & 256) ? -S : S;
  a21[14] = (t & 1)  ? -S : S;     // t bits = g6..g12 -> q14..q8
  a21[13] = (t & 2)  ? -S : S;
  a21[12] = (t & 4)  ? -S : S;
  a21[11] = (t & 8)  ? -S : S;
  a21[10] = (t & 16) ? -S : S;
  a21[9]  = (t & 32) ? -S : S;
  a21[8]  = (t & 64) ? -S : S;

  const int wv = tid >> 6;
#pragma unroll
  for (int q = 0; q < 21; ++q) {
    float val = a21[q];
    val += __shfl_down(val, 32);
    val += __shfl_down(val, 16);
    val += __shfl_down(val, 8);
    val += __shfl_down(val, 4);
    val += __shfl_down(val, 2);
    val += __shfl_down(val, 1);
    if (lane == 0) s[q * 8 + wv] = val;
  }
  __syncthreads();
  if (tid < NQ) {
    float sum = 0.f;
#pragma unroll
    for (int k = 0; k < 8; ++k) sum += s[tid * 8 + k];
    partial[((b << 7) | t) * NQ + tid] = sum;
  }
}

// ---------------- deterministic final reduction (1 block x 672) ----------------
__global__ void k_red(const float* __restrict__ partial, float* __restrict__ out) {
  __shared__ float red[84][8];
  const int tid = threadIdx.x;
  const int pair = tid >> 3, k8 = tid & 7;
  if (pair < 84) {
    int b = pair / NQ, q = pair % NQ;
    float sum = 0.f;
#pragma unroll
    for (int i = 0; i < 16; ++i) sum += partial[(b * 128 + k8 * 16 + i) * NQ + q];
    red[pair][k8] = sum;
  }
  __syncthreads();
  if (tid < 84) {
    float sum = 0.f;
#pragma unroll
    for (int k = 0; k < 8; ++k) sum += red[tid][k];
    out[tid] = sum;     // tid == b*21 + q
  }
}

extern "C" void kernel_launch(void* const* d_in, const int* in_sizes, int n_in,
                              void* d_out, int out_size, void* d_ws, size_t ws_size,
                              hipStream_t stream) {
  const float* x = (const float*)d_in[0];   // (4,21) f32
  const float* w = (const float*)d_in[1];   // (3,21) f32
  float* out = (float*)d_out;               // (4,21) f32
  unsigned long long stp = (unsigned long long)d_ws;            // 16 MB fp16 state
  float* partial = (float*)((char*)d_ws + (((size_t)4 << 21) * 2));  // 512*21 f32
  if (ws_size < ((size_t)4 << 21) * 2 + 512 * NQ * 4) return;

  dim3 grid(512), blk(512);
  k_L<true> <<<grid, blk, 0, stream>>>(x, w +  0, stp);
  k_H       <<<grid, blk, 0, stream>>>(w +  0, stp);
  k_L<false><<<grid, blk, 0, stream>>>(nullptr, w + 21, stp);
  k_H       <<<grid, blk, 0, stream>>>(w + 21, stp);
  k_L<false><<<grid, blk, 0, stream>>>(nullptr, w + 42, stp);
  k_Hfin    <<<grid, blk, 0, stream>>>(w + 42, stp, partial);
  k_red     <<<1, dim3(672), 0, stream>>>(partial, out);
}